// Round 12
// baseline (391.330 us; speedup 1.0000x reference)
//
#include <hip/hip_runtime.h>
#include <hip/hip_fp16.h>

#define H1 15
#define H2 81
#define FXS 10
#define FXT 5
#define FE 10
#define FU 10

#define BSH 5                 // 32 nodes per bucket
#define NPB 32
#define MAXBUK 4096           // supports NS up to 131072
#define ABLK 2048             // edges per k_mlpbin block
#define TB1 1024              // producer threads (16 waves)

typedef _Float16 half4 __attribute__((ext_vector_type(4)));
typedef float floatx4 __attribute__((ext_vector_type(4)));
typedef unsigned int uint;
typedef unsigned short ushort;

__device__ __forceinline__ _Float16 u2h(ushort v) {
    union { ushort u; _Float16 h; } c; c.u = v; return c.h;
}

// ---------- bucket histogram ----------
__global__ __launch_bounds__(256) void k_bhist(const int* __restrict__ src,
                                               int* __restrict__ bcnt, int E, int nbuk) {
    __shared__ int h[MAXBUK];
    for (int i = threadIdx.x; i < MAXBUK; i += 256) h[i] = 0;
    __syncthreads();
    for (int i = blockIdx.x * blockDim.x + threadIdx.x; i < E; i += gridDim.x * blockDim.x)
        atomicAdd(&h[src[i] >> BSH], 1);
    __syncthreads();
    for (int i = threadIdx.x; i < nbuk; i += 256)
        if (h[i]) atomicAdd(&bcnt[i], h[i]);
}

// ---------- bucket exclusive scan (1 block, 1024 thr, 4096 entries) ----------
__global__ __launch_bounds__(1024) void k_bscan(const int* __restrict__ bcnt,
                                                int* __restrict__ boffs,
                                                int* __restrict__ bcur, int nbuk) {
    __shared__ int sc[MAXBUK];
    int t = threadIdx.x;
#pragma unroll
    for (int k = 0; k < 4; k++) {
        int i = t + 1024 * k;
        sc[i] = (i < nbuk) ? bcnt[i] : 0;
    }
    __syncthreads();
    for (int d = 1; d < MAXBUK; d <<= 1) {
        int v[4];
#pragma unroll
        for (int k = 0; k < 4; k++) {
            int i = t + 1024 * k;
            v[k] = sc[i] + ((i >= d) ? sc[i - d] : 0);
        }
        __syncthreads();
#pragma unroll
        for (int k = 0; k < 4; k++) sc[t + 1024 * k] = v[k];
        __syncthreads();
    }
#pragma unroll
    for (int k = 0; k < 4; k++) {
        int i = t + 1024 * k;
        if (i < nbuk) {
            int o = sc[i] - bcnt[i];
            boffs[i] = o;
            bcur[i] = o;
        }
    }
}

// ---------- edge-order MFMA MLP + LDS bucket binning (round-11, proven) ----------
// record (32B): h[0..14] = fp16 edge-MLP outputs, h[15] = src_local (u16, 0..31)
__global__ __launch_bounds__(TB1, 1) void k_mlpbin(
    const float* __restrict__ x_t, const float* __restrict__ ea,
    const float* __restrict__ W1, const float* __restrict__ b1,
    const float* __restrict__ W2, const float* __restrict__ b2,
    const int* __restrict__ src, const int* __restrict__ tgt,
    int* __restrict__ bcur, uint* __restrict__ gbin, int E)
{
    __shared__ ushort stag[ABLK][16];
    __shared__ int A[MAXBUK];        // histogram -> (gb - st)
    __shared__ int B[MAXBUK];        // inclusive scan -> cursor
    __shared__ ushort sbk[ABLK];
    __shared__ ushort lds_f[TB1][20];
    __shared__ ushort lds_pos[TB1];

    int t = threadIdx.x;
    int base = blockIdx.x * ABLK;
    int m = min(ABLK, E - base);

#pragma unroll
    for (int k = 0; k < 4; k++) A[t + 1024 * k] = 0;
    __syncthreads();
    for (int i = t; i < m; i += TB1) atomicAdd(&A[src[base + i] >> BSH], 1);
    __syncthreads();
#pragma unroll
    for (int k = 0; k < 4; k++) { int i = t + 1024 * k; B[i] = A[i]; }
    __syncthreads();
    for (int d = 1; d < MAXBUK; d <<= 1) {
        int v[4];
#pragma unroll
        for (int k = 0; k < 4; k++) {
            int i = t + 1024 * k;
            v[k] = B[i] + ((i >= d) ? B[i - d] : 0);
        }
        __syncthreads();
#pragma unroll
        for (int k = 0; k < 4; k++) B[t + 1024 * k] = v[k];
        __syncthreads();
    }
#pragma unroll
    for (int k = 0; k < 4; k++) {
        int i = t + 1024 * k;
        int h = A[i];
        int st = B[i] - h;
        B[i] = st;
        int gb = h ? atomicAdd(&bcur[i], h) : 0;
        A[i] = gb - st;
    }
    __syncthreads();

    int lane = t & 63, w = t >> 6;
    int em = lane & 15;
    int kb = (lane >> 4) << 2;
    half4 a1f, a2f;
    floatx4 c1f, c2f;
#pragma unroll
    for (int i = 0; i < 4; i++) {
        int kk = kb + i;
        bool wv = (kk < H1) && (em < H1);
        a1f[i] = wv ? (_Float16)W1[kk * H1 + em] : (_Float16)0.f;
        a2f[i] = wv ? (_Float16)W2[kk * H1 + em] : (_Float16)0.f;
        c1f[i] = (kk < H1) ? b1[kk] : 0.f;
        c2f[i] = (kk < H1) ? b2[kk] : 0.f;
    }

#pragma unroll
    for (int p = 0; p < ABLK / TB1; p++) {
        int ti = p * TB1 + t;
        if (ti < m) {
            int e = base + ti;
            int sv = src[e], tg = tgt[e];
            int bk = sv >> BSH;
            int pos = atomicAdd(&B[bk], 1);
            lds_pos[t] = (ushort)pos;
            sbk[pos] = (ushort)bk;
            stag[pos][15] = (ushort)(sv & (NPB - 1));
            float f[16];
            const float* xr = x_t + (size_t)tg * FXT;
#pragma unroll
            for (int i = 0; i < FXT; i++) f[i] = xr[i];
            const float2* er = (const float2*)(ea + (size_t)e * FE);
#pragma unroll
            for (int i = 0; i < FE / 2; i++) {
                float2 v = er[i];
                f[FXT + 2 * i] = v.x;
                f[FXT + 2 * i + 1] = v.y;
            }
            f[15] = 0.f;
#pragma unroll
            for (int c = 0; c < 4; c++) {
                half4 hv;
#pragma unroll
                for (int i = 0; i < 4; i++) hv[i] = (_Float16)f[c * 4 + i];
                *(half4*)&lds_f[t][c * 4] = hv;
            }
        }
        __syncthreads();

#pragma unroll
        for (int g = 0; g < 4; g++) {
            int tt = w * 64 + g * 16 + em;
            half4 bf = *(const half4*)&lds_f[tt][kb];
            floatx4 d1 = __builtin_amdgcn_mfma_f32_16x16x16f16(a1f, bf, c1f, 0, 0, 0);
            half4 h;
#pragma unroll
            for (int i = 0; i < 4; i++) {
                float x = d1[i];
                x = fmaxf(x, 0.1f * x);
                h[i] = (_Float16)x;
            }
            floatx4 d2 = __builtin_amdgcn_mfma_f32_16x16x16f16(a2f, h, c2f, 0, 0, 0);
            if (p * TB1 + tt < m) {
                int pos = lds_pos[tt];
                union { _Float16 hh[4]; uint u[2]; } pk;
#pragma unroll
                for (int i = 0; i < 4; i++) pk.hh[i] = (_Float16)d2[i];
                if (kb < 12) {
                    *(uint2*)&stag[pos][kb] = make_uint2(pk.u[0], pk.u[1]);
                } else {
                    *(uint*)&stag[pos][12] = pk.u[0];
                    stag[pos][14] = (ushort)__half_as_ushort(__float2half((float)pk.hh[2]));
                }
            }
        }
        __syncthreads();
    }

    for (int i = t; i < m; i += TB1) {
        int bk = sbk[i];
        uint4 r0 = *(uint4*)&stag[i][0];
        uint4 r1 = *(uint4*)&stag[i][8];
        size_t dst = (size_t)(A[bk] + i) * 8;
        *(uint4*)(gbin + dst) = r0;
        *(uint4*)(gbin + dst + 4) = r1;
    }
}

// ---------- consumer: one-hot-MFMA segmented moments + node MLP ----------
// Wave = one 32-node bucket. Per 16-record chunk:
//   A_lo/A_hi = one-hot membership (16x16), B = x^p columns, D += A*B.
// D[node][col] accumulates s1..s4 for all 15 features + count (col 60).
__global__ __launch_bounds__(256, 3) void k_accF(
    const float* __restrict__ x_s, const float* __restrict__ u,
    const float* __restrict__ W3, const float* __restrict__ b3,
    const float* __restrict__ W4, const float* __restrict__ b4,
    const int* __restrict__ batch_s,
    const int* __restrict__ bcnt, const int* __restrict__ boffs,
    const uint* __restrict__ gbin,
    float* __restrict__ out, int NSs, int nbuk)
{
    __shared__ float sW3[H2 * FXS], sb3[FXS], sW4[FXS * FXS], sb4[FXS];
    __shared__ ushort stage[4][2][16][20];   // wave, dbuf, record, 16 halves (+pad)
    __shared__ float dmat[4][32 * 61];       // wave: 32 nodes x (60 moments + count)
    __shared__ float l1s[128][12];

    int t = threadIdx.x;
    for (int i = t; i < H2 * FXS; i += 256) sW3[i] = W3[i];
    for (int i = t; i < FXS * FXS; i += 256) sW4[i] = W4[i];
    if (t < FXS) { sb3[t] = b3[t]; sb4[t] = b4[t]; }

    int lane = t & 63, wv = t >> 6;
    int b = blockIdx.x * 4 + wv;
    int base = 0, cnt = 0;
    if (b < nbuk) { base = boffs[b]; cnt = bcnt[b]; }
    const uint* rb = gbin + (size_t)base * 8;

    int em = lane & 15;           // A row (node m) / B,D col
    int kb = (lane >> 4) << 2;    // k-base (A,B) / D row-base
    int rec = lane >> 2;          // staging record slot
    int part = lane & 3;          // staging uint2 part
    int p = em & 3;               // power index (0..3 -> x^1..x^4)
    int fq = em >> 2;             // feature-within-colgroup

    floatx4 aL0 = {0,0,0,0}, aL1 = {0,0,0,0}, aL2 = {0,0,0,0}, aL3 = {0,0,0,0};
    floatx4 aH0 = {0,0,0,0}, aH1 = {0,0,0,0}, aH2 = {0,0,0,0}, aH3 = {0,0,0,0};

    int nch = (cnt + 15) >> 4;
    uint2 pre = make_uint2(0u, 0u);
    if (nch > 0) {
        pre = (rec < cnt) ? *(const uint2*)(rb + (size_t)rec * 8 + part * 2)
                          : make_uint2(0u, 0u);
    }
    for (int ch = 0; ch < nch; ch++) {
        int pb = ch & 1;
        *(uint2*)&stage[wv][pb][rec][part * 4] = pre;     // 512B chunk, wave-local
        if (ch + 1 < nch) {
            int idx = (ch + 1) * 16 + rec;
            pre = (idx < cnt) ? *(const uint2*)(rb + (size_t)idx * 8 + part * 2)
                              : make_uint2(0u, 0u);
        }
        // one-hot A fragments (invalid recs have zero B cols -> harmless)
        half4 alo, ahi;
#pragma unroll
        for (int i = 0; i < 4; i++) {
            int sl = (int)stage[wv][pb][kb + i][15];
            alo[i] = (sl == em) ? (_Float16)1.f : (_Float16)0.f;
            ahi[i] = (sl == em + 16) ? (_Float16)1.f : (_Float16)0.f;
        }
        int kgbase = (ch << 4) + kb;
#define DO_Q(Q, AL, AH) { \
        half4 bq; \
        _Pragma("unroll") \
        for (int i = 0; i < 4; i++) { \
            _Float16 v; \
            if (Q == 3 && fq == 3) { \
                v = (p == 0 && (kgbase + i) < cnt) ? (_Float16)1.f : (_Float16)0.f; \
            } else { \
                _Float16 x = u2h(stage[wv][pb][kb + i][Q * 4 + fq]); \
                _Float16 x2 = x * x; \
                v = (p == 0) ? x : (p == 1) ? x2 \
                    : (p == 2) ? (_Float16)(x2 * x) : (_Float16)(x2 * x2); \
            } \
            bq[i] = v; \
        } \
        AL = __builtin_amdgcn_mfma_f32_16x16x16f16(alo, bq, AL, 0, 0, 0); \
        AH = __builtin_amdgcn_mfma_f32_16x16x16f16(ahi, bq, AH, 0, 0, 0); }
        DO_Q(0, aL0, aH0)
        DO_Q(1, aL1, aH1)
        DO_Q(2, aL2, aH2)
        DO_Q(3, aL3, aH3)
#undef DO_Q
    }

    // spill D to dmat: node = kb+i (+16 hi), col = Q*16 + em (<= 60)
#define SPILL(Q, AL, AH) { \
        int col = Q * 16 + em; \
        if (col <= 60) { \
            _Pragma("unroll") \
            for (int i = 0; i < 4; i++) { \
                dmat[wv][(kb + i) * 61 + col] = AL[i]; \
                dmat[wv][(kb + i + 16) * 61 + col] = AH[i]; \
            } \
        } }
    SPILL(0, aL0, aH0)
    SPILL(1, aL1, aH1)
    SPILL(2, aL2, aH2)
    SPILL(3, aL3, aH3)
#undef SPILL

    // stats in place (wave-local): arow[f*4+0..3] <- a, b, c, d
    {
        int nd = lane & 31, hf = lane >> 5;
        float* arow = &dmat[wv][nd * 61];
        float n = arow[60];
        float inv = 1.0f / fmaxf(n, 1.0f);
        for (int f = hf; f < H1; f += 2) {
            float s1 = arow[f * 4 + 0], s2 = arow[f * 4 + 1];
            float s3 = arow[f * 4 + 2], s4 = arow[f * 4 + 3];
            float a = s1 * inv, m2 = s2 * inv, m3 = s3 * inv, m4 = s4 * inv;
            float a2 = a * a;
            float var = m2 - a2;
            float bb = sqrtf(1e-6f + fmaxf(var, 0.0f));
            float c3 = m3 - 3.0f * a * m2 + 2.0f * a * a2;
            float c4 = m4 - 4.0f * a * m3 + 6.0f * a2 * m2 - 3.0f * a2 * a2;
            float ib = 1.0f / bb, ib2 = ib * ib;
            arow[f * 4 + 0] = a;
            arow[f * 4 + 1] = bb;
            arow[f * 4 + 2] = c3 * ib * ib2;
            arow[f * 4 + 3] = c4 * ib2 * ib2;
        }
    }
    __syncthreads();

    // node MLP layer 1 over the block's 128 nodes (feat assembled on the fly)
    for (int idx = t; idx < 128 * FXS; idx += 256) {
        int g = idx / FXS, j = idx - g * FXS;
        int s = blockIdx.x * 128 + g;
        if (s >= NSs) continue;
        const float* ar = &dmat[g >> 5][(g & 31) * 61];
        float acc = sb3[j];
        const float* xr = x_s + (size_t)s * FXS;
#pragma unroll
        for (int i = 0; i < FXS; i++) acc = fmaf(xr[i], sW3[i * FXS + j], acc);
        acc = fmaf(ar[60], sW3[FXS * FXS + j], acc);
#pragma unroll
        for (int f = 0; f < H1; f++) {
            acc = fmaf(ar[f * 4 + 0], sW3[(11 + f) * FXS + j], acc);
            acc = fmaf(ar[f * 4 + 1], sW3[(26 + f) * FXS + j], acc);
            acc = fmaf(ar[f * 4 + 2], sW3[(41 + f) * FXS + j], acc);
            acc = fmaf(ar[f * 4 + 3], sW3[(56 + f) * FXS + j], acc);
        }
        const float* ur = u + (size_t)batch_s[s] * FU;
#pragma unroll
        for (int i = 0; i < FU; i++) acc = fmaf(ur[i], sW3[(71 + i) * FXS + j], acc);
        l1s[g][j] = fmaxf(acc, 0.1f * acc);
    }
    __syncthreads();

    for (int idx = t; idx < 128 * FXS; idx += 256) {
        int g = idx / FXS, j = idx - g * FXS;
        int s = blockIdx.x * 128 + g;
        if (s >= NSs) continue;
        float acc = sb4[j];
#pragma unroll
        for (int i = 0; i < FXS; i++) acc = fmaf(l1s[g][i], sW4[i * FXS + j], acc);
        out[(size_t)s * FXS + j] = acc;
    }
}

extern "C" void kernel_launch(void* const* d_in, const int* in_sizes, int n_in,
                              void* d_out, int out_size, void* d_ws, size_t ws_size,
                              hipStream_t stream) {
    const float* x_s = (const float*)d_in[0];
    const float* x_t = (const float*)d_in[1];
    const float* ea  = (const float*)d_in[2];
    const float* u   = (const float*)d_in[3];
    const float* W1  = (const float*)d_in[4];
    const float* b1  = (const float*)d_in[5];
    const float* W2  = (const float*)d_in[6];
    const float* b2  = (const float*)d_in[7];
    const float* W3  = (const float*)d_in[8];
    const float* b3  = (const float*)d_in[9];
    const float* W4  = (const float*)d_in[10];
    const float* b4  = (const float*)d_in[11];
    const int* src   = (const int*)d_in[12];
    const int* tgt   = (const int*)d_in[13];
    const int* batch_s = (const int*)d_in[14];

    int NSs = in_sizes[0] / FXS;
    int E   = in_sizes[2] / FE;
    int nbuk = (NSs + NPB - 1) >> BSH;

    auto align_up = [](size_t x) { return (x + 255) & ~(size_t)255; };
    char* w = (char*)d_ws;
    int* bcnt  = (int*)w; w += align_up((size_t)MAXBUK * 4);
    int* boffs = (int*)w; w += align_up((size_t)MAXBUK * 4);
    int* bcur  = (int*)w; w += align_up((size_t)MAXBUK * 4);
    uint* gbin = (uint*)w;   // E * 32 bytes

    hipMemsetAsync(bcnt, 0, (size_t)MAXBUK * 4, stream);

    k_bhist<<<512, 256, 0, stream>>>(src, bcnt, E, nbuk);
    k_bscan<<<1, 1024, 0, stream>>>(bcnt, boffs, bcur, nbuk);
    k_mlpbin<<<(E + ABLK - 1) / ABLK, TB1, 0, stream>>>(
        x_t, ea, W1, b1, W2, b2, src, tgt, bcur, gbin, E);
    k_accF<<<(nbuk + 3) / 4, 256, 0, stream>>>(
        x_s, u, W3, b3, W4, b4, batch_s, bcnt, boffs, gbin,
        (float*)d_out, NSs, nbuk);
}

// Round 13
// 288.295 us; speedup vs baseline: 1.3574x; 1.3574x over previous
//
#include <hip/hip_runtime.h>
#include <hip/hip_fp16.h>

#define H1 15
#define H2 81
#define FXS 10
#define FXT 5
#define FE 10
#define FU 10

#define BSH 7                 // 128 nodes per coarse bucket
#define NPB 128
#define MAXBUK 1024           // supports NS up to 131072
#define ABLK 2048             // edges per k_mlpbin block
#define TB1 1024              // producer threads (16 waves)
#define TBS 1024              // splitter threads
#define RPT 5                 // records per splitter thread (CAP 5120 = mean+16sigma)
#define CAPS (TBS * RPT)

typedef _Float16 half4 __attribute__((ext_vector_type(4)));
typedef float floatx4 __attribute__((ext_vector_type(4)));
typedef unsigned int uint;
typedef unsigned short ushort;

// ---------- bucket histogram ----------
__global__ __launch_bounds__(256) void k_bhist(const int* __restrict__ src,
                                               int* __restrict__ bcnt, int E, int nbuk) {
    __shared__ int h[MAXBUK];
    for (int i = threadIdx.x; i < MAXBUK; i += 256) h[i] = 0;
    __syncthreads();
    for (int i = blockIdx.x * blockDim.x + threadIdx.x; i < E; i += gridDim.x * blockDim.x)
        atomicAdd(&h[src[i] >> BSH], 1);
    __syncthreads();
    for (int i = threadIdx.x; i < nbuk; i += 256)
        if (h[i]) atomicAdd(&bcnt[i], h[i]);
}

// ---------- bucket exclusive scan ----------
__global__ __launch_bounds__(1024) void k_bscan(const int* __restrict__ bcnt,
                                                int* __restrict__ boffs,
                                                int* __restrict__ bcur, int nbuk) {
    __shared__ int sc[MAXBUK];
    int t = threadIdx.x;
    int v = (t < nbuk) ? bcnt[t] : 0;
    sc[t] = v;
    __syncthreads();
    for (int d = 1; d < MAXBUK; d <<= 1) {
        int add = (t >= d) ? sc[t - d] : 0;
        __syncthreads();
        sc[t] += add;
        __syncthreads();
    }
    if (t < nbuk) { int o = sc[t] - v; boffs[t] = o; bcur[t] = o; }
}

// ---------- P1: edge-order MFMA MLP + LDS bucket binning (verbatim round-8, proven) ----------
// record (32B): h[0..14] = fp16 edge-MLP outputs, h[15] = src_local (u16, 0..127)
__global__ __launch_bounds__(TB1, 1) void k_mlpbin(
    const float* __restrict__ x_t, const float* __restrict__ ea,
    const float* __restrict__ W1, const float* __restrict__ b1,
    const float* __restrict__ W2, const float* __restrict__ b2,
    const int* __restrict__ src, const int* __restrict__ tgt,
    int* __restrict__ bcur, uint* __restrict__ gbin, int E)
{
    __shared__ ushort stag[ABLK][16];                  // 64 KB
    __shared__ int bh[MAXBUK], sc[MAXBUK], bc[MAXBUK], gb[MAXBUK];  // 16 KB
    __shared__ ushort sbk[ABLK];                       // 4 KB
    __shared__ ushort lds_f[TB1][20];                  // 40 KB, 40B stride
    __shared__ ushort lds_pos[TB1];                    // 2 KB

    int t = threadIdx.x;
    int base = blockIdx.x * ABLK;
    int m = min(ABLK, E - base);

    if (t < MAXBUK) bh[t] = 0;
    __syncthreads();
    for (int i = t; i < m; i += TB1) atomicAdd(&bh[src[base + i] >> BSH], 1);
    __syncthreads();
    if (t < MAXBUK) sc[t] = bh[t];
    __syncthreads();
    for (int d = 1; d < MAXBUK; d <<= 1) {
        int add = (t < MAXBUK && t >= d) ? sc[t - d] : 0;
        __syncthreads();
        if (t < MAXBUK) sc[t] += add;
        __syncthreads();
    }
    if (t < MAXBUK) {
        int h = bh[t];
        int st = sc[t] - h;
        sc[t] = st;
        bc[t] = st;
        gb[t] = h ? atomicAdd(&bcur[t], h) : 0;
    }
    __syncthreads();

    // resident weight/bias fragments (layout HW-verified rounds 4-12)
    int lane = t & 63, w = t >> 6;
    int em = lane & 15;
    int kb = (lane >> 4) << 2;
    half4 a1f, a2f;
    floatx4 c1f, c2f;
#pragma unroll
    for (int i = 0; i < 4; i++) {
        int kk = kb + i;
        bool wv = (kk < H1) && (em < H1);
        a1f[i] = wv ? (_Float16)W1[kk * H1 + em] : (_Float16)0.f;
        a2f[i] = wv ? (_Float16)W2[kk * H1 + em] : (_Float16)0.f;
        c1f[i] = (kk < H1) ? b1[kk] : 0.f;
        c2f[i] = (kk < H1) ? b2[kk] : 0.f;
    }

#pragma unroll
    for (int p = 0; p < ABLK / TB1; p++) {
        int ti = p * TB1 + t;
        if (ti < m) {
            int e = base + ti;
            int sv = src[e], tg = tgt[e];
            int bk = sv >> BSH;
            int pos = atomicAdd(&bc[bk], 1);
            lds_pos[t] = (ushort)pos;
            sbk[pos] = (ushort)bk;
            stag[pos][15] = (ushort)(sv & (NPB - 1));
            float f[16];
            const float* xr = x_t + (size_t)tg * FXT;
#pragma unroll
            for (int i = 0; i < FXT; i++) f[i] = xr[i];
            const float2* er = (const float2*)(ea + (size_t)e * FE);
#pragma unroll
            for (int i = 0; i < FE / 2; i++) {
                float2 v = er[i];
                f[FXT + 2 * i] = v.x;
                f[FXT + 2 * i + 1] = v.y;
            }
            f[15] = 0.f;
#pragma unroll
            for (int c = 0; c < 4; c++) {
                half4 hv;
#pragma unroll
                for (int i = 0; i < 4; i++) hv[i] = (_Float16)f[c * 4 + i];
                *(half4*)&lds_f[t][c * 4] = hv;
            }
        }
        __syncthreads();

#pragma unroll
        for (int g = 0; g < 4; g++) {
            int tt = w * 64 + g * 16 + em;
            half4 bf = *(const half4*)&lds_f[tt][kb];
            floatx4 d1 = __builtin_amdgcn_mfma_f32_16x16x16f16(a1f, bf, c1f, 0, 0, 0);
            half4 h;
#pragma unroll
            for (int i = 0; i < 4; i++) {
                float x = d1[i];
                x = fmaxf(x, 0.1f * x);
                h[i] = (_Float16)x;
            }
            floatx4 d2 = __builtin_amdgcn_mfma_f32_16x16x16f16(a2f, h, c2f, 0, 0, 0);
            if (p * TB1 + tt < m) {
                int pos = lds_pos[tt];
                union { _Float16 hh[4]; uint u[2]; } pk;
#pragma unroll
                for (int i = 0; i < 4; i++) pk.hh[i] = (_Float16)d2[i];
                if (kb < 12) {
                    *(uint2*)&stag[pos][kb] = make_uint2(pk.u[0], pk.u[1]);
                } else {
                    *(uint*)&stag[pos][12] = pk.u[0];
                    stag[pos][14] = (ushort)__half_as_ushort(__float2half((float)pk.hh[2]));
                }
            }
        }
        __syncthreads();
    }

    for (int i = t; i < m; i += TB1) {
        int bk = sbk[i];
        uint4 r0 = *(uint4*)&stag[i][0];
        uint4 r1 = *(uint4*)&stag[i][8];
        size_t dst = (size_t)(gb[bk] + (i - sc[bk])) * 8;
        *(uint4*)(gbin + dst) = r0;
        *(uint4*)(gbin + dst + 4) = r1;
    }
}

// ---------- P2: per-bucket IN-PLACE node sort (register-staged) ----------
// Reads its whole window into registers (sid extraction forces load completion
// before the first barrier), scans 128 node counters, writes records back into
// the SAME window in node order. 32B scatters span <=164KB -> L2-merged.
// Emits per-node (start, count) for the consumer.
__global__ __launch_bounds__(TBS) void k_split(
    const int* __restrict__ bcnt, const int* __restrict__ boffs,
    uint* __restrict__ gbin, int* __restrict__ nstart, int* __restrict__ ncnt,
    int NSs)
{
    __shared__ int fh[NPB], fstart[NPB], fcur[NPB];
    int t = threadIdx.x;
    int b = blockIdx.x;
    int base = boffs[b];
    int cnt = min(bcnt[b], CAPS);
    if (t < NPB) fh[t] = 0;
    __syncthreads();

    uint* rb = gbin + (size_t)base * 8;
    uint4 r0[RPT], r1[RPT];
    int sid[RPT];
#pragma unroll
    for (int c = 0; c < RPT; c++) {
        int i = t + c * TBS;
        sid[c] = -1;
        if (i < cnt) {
            r0[c] = *(const uint4*)(rb + (size_t)i * 8);
            r1[c] = *(const uint4*)(rb + (size_t)i * 8 + 4);
            sid[c] = (int)(r1[c].w >> 16) & (NPB - 1);
            atomicAdd(&fh[sid[c]], 1);
        }
    }
    __syncthreads();
    if (t < NPB) fstart[t] = fh[t];
    __syncthreads();
    for (int d = 1; d < NPB; d <<= 1) {
        int add = (t < NPB && t >= d) ? fstart[t - d] : 0;
        __syncthreads();
        if (t < NPB) fstart[t] += add;
        __syncthreads();
    }
    if (t < NPB) {
        int st = fstart[t] - fh[t];
        fstart[t] = st;
        fcur[t] = st;
        int node = (b << BSH) + t;
        if (node < NSs) { nstart[node] = base + st; ncnt[node] = fh[t]; }
    }
    __syncthreads();
#pragma unroll
    for (int c = 0; c < RPT; c++) {
        if (sid[c] >= 0) {
            int p = atomicAdd(&fcur[sid[c]], 1);
            uint* dst = rb + (size_t)p * 8;
            *(uint4*)dst = r0[c];
            *(uint4*)(dst + 4) = r1[c];
        }
    }
}

// ---------- P3: thread-per-node streaming moments + node MLP ----------
// Node's records are contiguous: serial 32B reads per thread (sequential within
// a 64B-line stream -> L1-friendly), 60 raw moments in registers, stats,
// then the 81->10->10 MLP with LDS-broadcast weights (epilogue verified R10).
__global__ __launch_bounds__(256) void k_node2(
    const float* __restrict__ x_s, const float* __restrict__ u,
    const float* __restrict__ W3, const float* __restrict__ b3,
    const float* __restrict__ W4, const float* __restrict__ b4,
    const int* __restrict__ batch_s,
    const int* __restrict__ nstart, const int* __restrict__ ncnt,
    const uint* __restrict__ gbin,
    float* __restrict__ out, int NSs)
{
    __shared__ float sW3[H2 * FXS], sb3[FXS], sW4[FXS * FXS], sb4[FXS];
    int t = threadIdx.x;
    for (int i = t; i < H2 * FXS; i += 256) sW3[i] = W3[i];
    for (int i = t; i < FXS * FXS; i += 256) sW4[i] = W4[i];
    if (t < FXS) { sb3[t] = b3[t]; sb4[t] = b4[t]; }
    __syncthreads();

    int s = blockIdx.x * 256 + t;
    if (s >= NSs) return;
    int n = ncnt[s], start = nstart[s];
    const uint* rp = gbin + (size_t)start * 8;

    float s1[H1], s2[H1], s3[H1], s4[H1];
#pragma unroll
    for (int f = 0; f < H1; f++) { s1[f] = 0.f; s2[f] = 0.f; s3[f] = 0.f; s4[f] = 0.f; }

    for (int k = 0; k < n; k++) {
        uint4 q0 = *(const uint4*)(rp + (size_t)k * 8);
        uint4 q1 = *(const uint4*)(rp + (size_t)k * 8 + 4);
        union { uint4 q; _Float16 h[8]; } ua, ub;
        ua.q = q0; ub.q = q1;
#pragma unroll
        for (int f = 0; f < 8; f++) {
            float x = (float)ua.h[f];
            float x2 = x * x;
            s1[f] += x;
            s2[f] = fmaf(x, x, s2[f]);
            s3[f] = fmaf(x2, x, s3[f]);
            s4[f] = fmaf(x2, x2, s4[f]);
        }
#pragma unroll
        for (int f = 8; f < H1; f++) {
            float x = (float)ub.h[f - 8];
            float x2 = x * x;
            s1[f] += x;
            s2[f] = fmaf(x, x, s2[f]);
            s3[f] = fmaf(x2, x, s3[f]);
            s4[f] = fmaf(x2, x2, s4[f]);
        }
    }

    float inv = 1.0f / (float)(n > 1 ? n : 1);
#pragma unroll
    for (int f = 0; f < H1; f++) {
        float a = s1[f] * inv, m2 = s2[f] * inv, m3 = s3[f] * inv, m4 = s4[f] * inv;
        float a2 = a * a;
        float var = m2 - a2;
        float bb = sqrtf(1e-6f + fmaxf(var, 0.0f));
        float c3 = m3 - 3.0f * a * m2 + 2.0f * a * a2;
        float c4 = m4 - 4.0f * a * m3 + 6.0f * a2 * m2 - 3.0f * a2 * a2;
        float ib = 1.0f / bb, ib2 = ib * ib;
        s1[f] = a;
        s2[f] = bb;
        s3[f] = c3 * ib * ib2;
        s4[f] = c4 * ib2 * ib2;
    }

    float xs[FXS], uu[FU];
    const float* xr = x_s + (size_t)s * FXS;
#pragma unroll
    for (int i = 0; i < FXS; i++) xs[i] = xr[i];
    const float* ur = u + (size_t)batch_s[s] * FU;
#pragma unroll
    for (int i = 0; i < FU; i++) uu[i] = ur[i];
    float nf = (float)n;

    float l1[FXS];
#pragma unroll
    for (int j = 0; j < FXS; j++) {
        float acc = sb3[j];
#pragma unroll
        for (int i = 0; i < FXS; i++) acc = fmaf(xs[i], sW3[i * FXS + j], acc);
        acc = fmaf(nf, sW3[FXS * FXS + j], acc);
#pragma unroll
        for (int f = 0; f < H1; f++) {
            acc = fmaf(s1[f], sW3[(11 + f) * FXS + j], acc);
            acc = fmaf(s2[f], sW3[(26 + f) * FXS + j], acc);
            acc = fmaf(s3[f], sW3[(41 + f) * FXS + j], acc);
            acc = fmaf(s4[f], sW3[(56 + f) * FXS + j], acc);
        }
#pragma unroll
        for (int i = 0; i < FU; i++) acc = fmaf(uu[i], sW3[(71 + i) * FXS + j], acc);
        l1[j] = fmaxf(acc, 0.1f * acc);
    }
#pragma unroll
    for (int j = 0; j < FXS; j++) {
        float acc = sb4[j];
#pragma unroll
        for (int i = 0; i < FXS; i++) acc = fmaf(l1[i], sW4[i * FXS + j], acc);
        out[(size_t)s * FXS + j] = acc;
    }
}

extern "C" void kernel_launch(void* const* d_in, const int* in_sizes, int n_in,
                              void* d_out, int out_size, void* d_ws, size_t ws_size,
                              hipStream_t stream) {
    const float* x_s = (const float*)d_in[0];
    const float* x_t = (const float*)d_in[1];
    const float* ea  = (const float*)d_in[2];
    const float* u   = (const float*)d_in[3];
    const float* W1  = (const float*)d_in[4];
    const float* b1  = (const float*)d_in[5];
    const float* W2  = (const float*)d_in[6];
    const float* b2  = (const float*)d_in[7];
    const float* W3  = (const float*)d_in[8];
    const float* b3  = (const float*)d_in[9];
    const float* W4  = (const float*)d_in[10];
    const float* b4  = (const float*)d_in[11];
    const int* src   = (const int*)d_in[12];
    const int* tgt   = (const int*)d_in[13];
    const int* batch_s = (const int*)d_in[14];

    int NSs = in_sizes[0] / FXS;
    int E   = in_sizes[2] / FE;
    int nbuk = (NSs + NPB - 1) >> BSH;

    auto align_up = [](size_t x) { return (x + 255) & ~(size_t)255; };
    char* w = (char*)d_ws;
    int* bcnt   = (int*)w; w += align_up((size_t)MAXBUK * 4);
    int* boffs  = (int*)w; w += align_up((size_t)MAXBUK * 4);
    int* bcur   = (int*)w; w += align_up((size_t)MAXBUK * 4);
    int* nstart = (int*)w; w += align_up((size_t)NSs * 4);
    int* ncnt   = (int*)w; w += align_up((size_t)NSs * 4);
    uint* gbin  = (uint*)w;   // E * 32 bytes

    hipMemsetAsync(bcnt, 0, (size_t)MAXBUK * 4, stream);

    k_bhist<<<512, 256, 0, stream>>>(src, bcnt, E, nbuk);
    k_bscan<<<1, 1024, 0, stream>>>(bcnt, boffs, bcur, nbuk);
    k_mlpbin<<<(E + ABLK - 1) / ABLK, TB1, 0, stream>>>(
        x_t, ea, W1, b1, W2, b2, src, tgt, bcur, gbin, E);
    k_split<<<nbuk, TBS, 0, stream>>>(bcnt, boffs, gbin, nstart, ncnt, NSs);
    k_node2<<<(NSs + 255) / 256, 256, 0, stream>>>(
        x_s, u, W3, b3, W4, b4, batch_s, nstart, ncnt, gbin, (float*)d_out, NSs);
}

// Round 14
// 275.019 us; speedup vs baseline: 1.4229x; 1.0483x over previous
//
#include <hip/hip_runtime.h>
#include <hip/hip_fp16.h>

#define H1 15
#define H2 81
#define FXS 10
#define FXT 5
#define FE 10
#define FU 10

#define BSH 7                 // 128 nodes per coarse bucket
#define NPB 128
#define MAXBUK 1024           // supports NS up to 131072
#define ABLK 2048             // edges per k_mlpbin block
#define TB1 1024              // producer threads (16 waves)
#define TBS 1024              // splitter threads
#define RPT 5                 // records per splitter thread
#define CAPS (TBS * RPT)

typedef _Float16 half4 __attribute__((ext_vector_type(4)));
typedef float floatx4 __attribute__((ext_vector_type(4)));
typedef unsigned int uint;
typedef unsigned short ushort;

// swizzled uint2 slot for record row/quarter: optimal bank spread for
// row-consecutive AND quarter-consecutive access patterns
__device__ __forceinline__ int sw(int row, int q) {
    return row * 8 + 2 * (q ^ ((row >> 2) & 3));
}

// ---------- bucket histogram ----------
__global__ __launch_bounds__(256) void k_bhist(const int* __restrict__ src,
                                               int* __restrict__ bcnt, int E, int nbuk) {
    __shared__ int h[MAXBUK];
    for (int i = threadIdx.x; i < MAXBUK; i += 256) h[i] = 0;
    __syncthreads();
    for (int i = blockIdx.x * blockDim.x + threadIdx.x; i < E; i += gridDim.x * blockDim.x)
        atomicAdd(&h[src[i] >> BSH], 1);
    __syncthreads();
    for (int i = threadIdx.x; i < nbuk; i += 256)
        if (h[i]) atomicAdd(&bcnt[i], h[i]);
}

// ---------- bucket exclusive scan ----------
__global__ __launch_bounds__(1024) void k_bscan(const int* __restrict__ bcnt,
                                                int* __restrict__ boffs,
                                                int* __restrict__ bcur, int nbuk) {
    __shared__ int sc[MAXBUK];
    int t = threadIdx.x;
    int v = (t < nbuk) ? bcnt[t] : 0;
    sc[t] = v;
    __syncthreads();
    for (int d = 1; d < MAXBUK; d <<= 1) {
        int add = (t >= d) ? sc[t - d] : 0;
        __syncthreads();
        sc[t] += add;
        __syncthreads();
    }
    if (t < nbuk) { int o = sc[t] - v; boffs[t] = o; bcur[t] = o; }
}

// ---------- P1: edge-order MFMA MLP + in-place LDS binning ----------
// record (32B): h[0..14] = fp16 edge-MLP outputs, h[15] = src_local (raw u16)
// Features staged DIRECTLY into swizzled stag rows at bin positions; MFMA
// computes in place (sid in k=15 hits zero-padded W rows; subnormal, no NaN).
__global__ __launch_bounds__(TB1, 8) void k_mlpbin(
    const float* __restrict__ x_t, const float* __restrict__ ea,
    const float* __restrict__ W1, const float* __restrict__ b1,
    const float* __restrict__ W2, const float* __restrict__ b2,
    const int* __restrict__ src, const int* __restrict__ tgt,
    int* __restrict__ bcur, uint* __restrict__ gbin, int E)
{
    __shared__ uint stagw[ABLK * 8];          // 64 KB, swizzled records
    __shared__ int A[MAXBUK];                 // hist -> (gb - st)
    __shared__ int B[MAXBUK];                 // cursor
    __shared__ ushort sbk[ABLK];              // 4 KB
    __shared__ int wsum[16];

    int t = threadIdx.x;
    int lane = t & 63, w = t >> 6;
    int base = blockIdx.x * ABLK;
    int m = min(ABLK, E - base);

    // ---- block histogram (TB1 == MAXBUK) ----
    A[t] = 0;
    __syncthreads();
    for (int i = t; i < m; i += TB1) atomicAdd(&A[src[base + i] >> BSH], 1);
    __syncthreads();

    // ---- 2-barrier shuffle scan over 1024 entries ----
    int h = A[t];
    int x = h;
#pragma unroll
    for (int d = 1; d < 64; d <<= 1) {
        int y = __shfl_up(x, d, 64);
        if (lane >= d) x += y;
    }
    if (lane == 63) wsum[w] = x;
    __syncthreads();
    if (w == 0) {
        int v = (lane < 16) ? wsum[lane] : 0;
        int xx = v;
#pragma unroll
        for (int d = 1; d < 16; d <<= 1) {
            int y = __shfl_up(xx, d, 64);
            if (lane >= d) xx += y;
        }
        if (lane < 16) wsum[lane] = xx - v;   // exclusive wave prefix
    }
    __syncthreads();
    int st = wsum[w] + (x - h);               // exclusive start of entry t
    B[t] = st;
    int gb = h ? atomicAdd(&bcur[t], h) : 0;
    A[t] = gb - st;                           // dst = A[bk] + bin_pos
    __syncthreads();

    // ---- resident weight/bias fragments (layout HW-verified rounds 4-13) ----
    int em = lane & 15;
    int kb = (lane >> 4) << 2;
    int q = kb >> 2;
    half4 a1f, a2f;
    floatx4 c1f, c2f;
#pragma unroll
    for (int i = 0; i < 4; i++) {
        int kk = kb + i;
        bool wv = (kk < H1) && (em < H1);
        a1f[i] = wv ? (_Float16)W1[kk * H1 + em] : (_Float16)0.f;
        a2f[i] = wv ? (_Float16)W2[kk * H1 + em] : (_Float16)0.f;
        c1f[i] = (kk < H1) ? b1[kk] : 0.f;
        c2f[i] = (kk < H1) ? b2[kk] : 0.f;
    }

    // ---- stage ALL edges: features -> swizzled stag rows at bin positions ----
    for (int i = t; i < m; i += TB1) {
        int e = base + i;
        int sv = src[e], tg = tgt[e];
        int bk = sv >> BSH;
        int pos = atomicAdd(&B[bk], 1);
        sbk[pos] = (ushort)bk;
        float f[15];
        const float* xr = x_t + (size_t)tg * FXT;
#pragma unroll
        for (int j = 0; j < FXT; j++) f[j] = xr[j];
        const float2* er = (const float2*)(ea + (size_t)e * FE);
#pragma unroll
        for (int j = 0; j < FE / 2; j++) {
            float2 v = er[j];
            f[FXT + 2 * j] = v.x;
            f[FXT + 2 * j + 1] = v.y;
        }
#pragma unroll
        for (int c = 0; c < 4; c++) {
            union { _Float16 hh[4]; ushort us[4]; uint2 u; } pk;
#pragma unroll
            for (int j = 0; j < 4; j++) {
                int fi = c * 4 + j;
                pk.hh[j] = (fi < 15) ? (_Float16)f[fi] : (_Float16)0.f;
            }
            if (c == 3) pk.us[3] = (ushort)(sv & (NPB - 1));   // sid (subnormal fp16)
            *(uint2*)&stagw[sw(pos, c)] = pk.u;
        }
    }
    __syncthreads();

    // ---- MFMA in place: 16 waves x 128 rows = 8 groups of 16 ----
#pragma unroll
    for (int g = 0; g < ABLK / (16 * 16); g++) {
        int r = w * 128 + g * 16 + em;
        union { uint2 u; _Float16 hh[4]; } bin_;
        bin_.u = *(uint2*)&stagw[sw(r, q)];
        half4 bf;
#pragma unroll
        for (int j = 0; j < 4; j++) bf[j] = bin_.hh[j];
        floatx4 d1 = __builtin_amdgcn_mfma_f32_16x16x16f16(a1f, bf, c1f, 0, 0, 0);
        half4 hm;
#pragma unroll
        for (int j = 0; j < 4; j++) {
            float xx = d1[j];
            xx = fmaxf(xx, 0.1f * xx);
            hm[j] = (_Float16)xx;
        }
        floatx4 d2 = __builtin_amdgcn_mfma_f32_16x16x16f16(a2f, hm, c2f, 0, 0, 0);
        union { _Float16 hh[4]; ushort us[4]; uint uu[2]; uint2 u; } ov;
#pragma unroll
        for (int j = 0; j < 4; j++) ov.hh[j] = (_Float16)d2[j];
        uint* wp = &stagw[sw(r, q)];
        if (kb < 12) {
            *(uint2*)wp = ov.u;
        } else {
            wp[0] = ov.uu[0];                       // h12,h13
            ((ushort*)&wp[1])[0] = ov.us[2];        // h14 (preserves sid in high half)
        }
    }
    __syncthreads();

    // ---- dense write-out: bin order -> bucket-contiguous global bursts ----
    for (int i = t; i < m; i += TB1) {
        int bk = sbk[i];
        uint2 q0 = *(uint2*)&stagw[sw(i, 0)];
        uint2 q1 = *(uint2*)&stagw[sw(i, 1)];
        uint2 q2 = *(uint2*)&stagw[sw(i, 2)];
        uint2 q3 = *(uint2*)&stagw[sw(i, 3)];
        size_t dst = (size_t)(A[bk] + i) * 8;
        *(uint4*)(gbin + dst)     = make_uint4(q0.x, q0.y, q1.x, q1.y);
        *(uint4*)(gbin + dst + 4) = make_uint4(q2.x, q2.y, q3.x, q3.y);
    }
}

// ---------- P2: per-bucket IN-PLACE node sort (register-staged, R13-proven) ----------
__global__ __launch_bounds__(TBS) void k_split(
    const int* __restrict__ bcnt, const int* __restrict__ boffs,
    uint* __restrict__ gbin, int* __restrict__ nstart, int* __restrict__ ncnt,
    int NSs)
{
    __shared__ int fh[NPB], fstart[NPB], fcur[NPB];
    int t = threadIdx.x;
    int b = blockIdx.x;
    int base = boffs[b];
    int cnt = min(bcnt[b], CAPS);
    if (t < NPB) fh[t] = 0;
    __syncthreads();

    uint* rb = gbin + (size_t)base * 8;
    uint4 r0[RPT], r1[RPT];
    int sid[RPT];
#pragma unroll
    for (int c = 0; c < RPT; c++) {
        int i = t + c * TBS;
        sid[c] = -1;
        if (i < cnt) {
            r0[c] = *(const uint4*)(rb + (size_t)i * 8);
            r1[c] = *(const uint4*)(rb + (size_t)i * 8 + 4);
            sid[c] = (int)(r1[c].w >> 16) & (NPB - 1);
            atomicAdd(&fh[sid[c]], 1);
        }
    }
    __syncthreads();
    if (t < NPB) fstart[t] = fh[t];
    __syncthreads();
    for (int d = 1; d < NPB; d <<= 1) {
        int add = (t < NPB && t >= d) ? fstart[t - d] : 0;
        __syncthreads();
        if (t < NPB) fstart[t] += add;
        __syncthreads();
    }
    if (t < NPB) {
        int st = fstart[t] - fh[t];
        fstart[t] = st;
        fcur[t] = st;
        int node = (b << BSH) + t;
        if (node < NSs) { nstart[node] = base + st; ncnt[node] = fh[t]; }
    }
    __syncthreads();
#pragma unroll
    for (int c = 0; c < RPT; c++) {
        if (sid[c] >= 0) {
            int p = atomicAdd(&fcur[sid[c]], 1);
            uint* dst = rb + (size_t)p * 8;
            *(uint4*)dst = r0[c];
            *(uint4*)(dst + 4) = r1[c];
        }
    }
}

// ---------- P3: thread-per-node streaming moments + node MLP (R13-proven) ----------
__global__ __launch_bounds__(256) void k_node2(
    const float* __restrict__ x_s, const float* __restrict__ u,
    const float* __restrict__ W3, const float* __restrict__ b3,
    const float* __restrict__ W4, const float* __restrict__ b4,
    const int* __restrict__ batch_s,
    const int* __restrict__ nstart, const int* __restrict__ ncnt,
    const uint* __restrict__ gbin,
    float* __restrict__ out, int NSs)
{
    __shared__ float sW3[H2 * FXS], sb3[FXS], sW4[FXS * FXS], sb4[FXS];
    int t = threadIdx.x;
    for (int i = t; i < H2 * FXS; i += 256) sW3[i] = W3[i];
    for (int i = t; i < FXS * FXS; i += 256) sW4[i] = W4[i];
    if (t < FXS) { sb3[t] = b3[t]; sb4[t] = b4[t]; }
    __syncthreads();

    int s = blockIdx.x * 256 + t;
    if (s >= NSs) return;
    int n = ncnt[s], start = nstart[s];
    const uint* rp = gbin + (size_t)start * 8;

    float s1[H1], s2[H1], s3[H1], s4[H1];
#pragma unroll
    for (int f = 0; f < H1; f++) { s1[f] = 0.f; s2[f] = 0.f; s3[f] = 0.f; s4[f] = 0.f; }

    for (int k = 0; k < n; k++) {
        uint4 q0 = *(const uint4*)(rp + (size_t)k * 8);
        uint4 q1 = *(const uint4*)(rp + (size_t)k * 8 + 4);
        union { uint4 q; _Float16 h[8]; } ua, ub;
        ua.q = q0; ub.q = q1;
#pragma unroll
        for (int f = 0; f < 8; f++) {
            float x = (float)ua.h[f];
            float x2 = x * x;
            s1[f] += x;
            s2[f] = fmaf(x, x, s2[f]);
            s3[f] = fmaf(x2, x, s3[f]);
            s4[f] = fmaf(x2, x2, s4[f]);
        }
#pragma unroll
        for (int f = 8; f < H1; f++) {
            float x = (float)ub.h[f - 8];
            float x2 = x * x;
            s1[f] += x;
            s2[f] = fmaf(x, x, s2[f]);
            s3[f] = fmaf(x2, x, s3[f]);
            s4[f] = fmaf(x2, x2, s4[f]);
        }
    }

    float inv = 1.0f / (float)(n > 1 ? n : 1);
#pragma unroll
    for (int f = 0; f < H1; f++) {
        float a = s1[f] * inv, m2 = s2[f] * inv, m3 = s3[f] * inv, m4 = s4[f] * inv;
        float a2 = a * a;
        float var = m2 - a2;
        float bb = sqrtf(1e-6f + fmaxf(var, 0.0f));
        float c3 = m3 - 3.0f * a * m2 + 2.0f * a * a2;
        float c4 = m4 - 4.0f * a * m3 + 6.0f * a2 * m2 - 3.0f * a2 * a2;
        float ib = 1.0f / bb, ib2 = ib * ib;
        s1[f] = a;
        s2[f] = bb;
        s3[f] = c3 * ib * ib2;
        s4[f] = c4 * ib2 * ib2;
    }

    float xs[FXS], uu[FU];
    const float* xr = x_s + (size_t)s * FXS;
#pragma unroll
    for (int i = 0; i < FXS; i++) xs[i] = xr[i];
    const float* ur = u + (size_t)batch_s[s] * FU;
#pragma unroll
    for (int i = 0; i < FU; i++) uu[i] = ur[i];
    float nf = (float)n;

    float l1[FXS];
#pragma unroll
    for (int j = 0; j < FXS; j++) {
        float acc = sb3[j];
#pragma unroll
        for (int i = 0; i < FXS; i++) acc = fmaf(xs[i], sW3[i * FXS + j], acc);
        acc = fmaf(nf, sW3[FXS * FXS + j], acc);
#pragma unroll
        for (int f = 0; f < H1; f++) {
            acc = fmaf(s1[f], sW3[(11 + f) * FXS + j], acc);
            acc = fmaf(s2[f], sW3[(26 + f) * FXS + j], acc);
            acc = fmaf(s3[f], sW3[(41 + f) * FXS + j], acc);
            acc = fmaf(s4[f], sW3[(56 + f) * FXS + j], acc);
        }
#pragma unroll
        for (int i = 0; i < FU; i++) acc = fmaf(uu[i], sW3[(71 + i) * FXS + j], acc);
        l1[j] = fmaxf(acc, 0.1f * acc);
    }
#pragma unroll
    for (int j = 0; j < FXS; j++) {
        float acc = sb4[j];
#pragma unroll
        for (int i = 0; i < FXS; i++) acc = fmaf(l1[i], sW4[i * FXS + j], acc);
        out[(size_t)s * FXS + j] = acc;
    }
}

extern "C" void kernel_launch(void* const* d_in, const int* in_sizes, int n_in,
                              void* d_out, int out_size, void* d_ws, size_t ws_size,
                              hipStream_t stream) {
    const float* x_s = (const float*)d_in[0];
    const float* x_t = (const float*)d_in[1];
    const float* ea  = (const float*)d_in[2];
    const float* u   = (const float*)d_in[3];
    const float* W1  = (const float*)d_in[4];
    const float* b1  = (const float*)d_in[5];
    const float* W2  = (const float*)d_in[6];
    const float* b2  = (const float*)d_in[7];
    const float* W3  = (const float*)d_in[8];
    const float* b3  = (const float*)d_in[9];
    const float* W4  = (const float*)d_in[10];
    const float* b4  = (const float*)d_in[11];
    const int* src   = (const int*)d_in[12];
    const int* tgt   = (const int*)d_in[13];
    const int* batch_s = (const int*)d_in[14];

    int NSs = in_sizes[0] / FXS;
    int E   = in_sizes[2] / FE;
    int nbuk = (NSs + NPB - 1) >> BSH;

    auto align_up = [](size_t x) { return (x + 255) & ~(size_t)255; };
    char* w = (char*)d_ws;
    int* bcnt   = (int*)w; w += align_up((size_t)MAXBUK * 4);
    int* boffs  = (int*)w; w += align_up((size_t)MAXBUK * 4);
    int* bcur   = (int*)w; w += align_up((size_t)MAXBUK * 4);
    int* nstart = (int*)w; w += align_up((size_t)NSs * 4);
    int* ncnt   = (int*)w; w += align_up((size_t)NSs * 4);
    uint* gbin  = (uint*)w;   // E * 32 bytes

    hipMemsetAsync(bcnt, 0, (size_t)MAXBUK * 4, stream);

    k_bhist<<<512, 256, 0, stream>>>(src, bcnt, E, nbuk);
    k_bscan<<<1, 1024, 0, stream>>>(bcnt, boffs, bcur, nbuk);
    k_mlpbin<<<(E + ABLK - 1) / ABLK, TB1, 0, stream>>>(
        x_t, ea, W1, b1, W2, b2, src, tgt, bcur, gbin, E);
    k_split<<<nbuk, TBS, 0, stream>>>(bcnt, boffs, gbin, nstart, ncnt, NSs);
    k_node2<<<(NSs + 255) / 256, 256, 0, stream>>>(
        x_s, u, W3, b3, W4, b4, batch_s, nstart, ncnt, gbin, (float*)d_out, NSs);
}

// Round 15
// 188.093 us; speedup vs baseline: 2.0805x; 1.4621x over previous
//
#include <hip/hip_runtime.h>
#include <hip/hip_fp16.h>

#define H1 15
#define H2 81
#define FXS 10
#define FXT 5
#define FE 10
#define FU 10

#define BSH 7                 // 128 nodes per coarse bucket
#define NPB 128
#define MAXBUK 1024           // supports NS up to 131072
#define ABLK 2048             // edges per k_mlpbin block
#define TB1 1024              // producer threads (16 waves)
#define TBF 512               // fused consumer threads
#define CAPS 5120             // records per bucket cap (mean 4092 + 16 sigma)

typedef _Float16 half4 __attribute__((ext_vector_type(4)));
typedef float floatx4 __attribute__((ext_vector_type(4)));
typedef unsigned int uint;
typedef unsigned short ushort;

// swizzled uint2 slot for record row/quarter (R14-proven)
__device__ __forceinline__ int sw(int row, int q) {
    return row * 8 + 2 * (q ^ ((row >> 2) & 3));
}

// ---------- bucket histogram ----------
__global__ __launch_bounds__(256) void k_bhist(const int* __restrict__ src,
                                               int* __restrict__ bcnt, int E, int nbuk) {
    __shared__ int h[MAXBUK];
    for (int i = threadIdx.x; i < MAXBUK; i += 256) h[i] = 0;
    __syncthreads();
    for (int i = blockIdx.x * blockDim.x + threadIdx.x; i < E; i += gridDim.x * blockDim.x)
        atomicAdd(&h[src[i] >> BSH], 1);
    __syncthreads();
    for (int i = threadIdx.x; i < nbuk; i += 256)
        if (h[i]) atomicAdd(&bcnt[i], h[i]);
}

// ---------- bucket exclusive scan ----------
__global__ __launch_bounds__(1024) void k_bscan(const int* __restrict__ bcnt,
                                                int* __restrict__ boffs,
                                                int* __restrict__ bcur, int nbuk) {
    __shared__ int sc[MAXBUK];
    int t = threadIdx.x;
    int v = (t < nbuk) ? bcnt[t] : 0;
    sc[t] = v;
    __syncthreads();
    for (int d = 1; d < MAXBUK; d <<= 1) {
        int add = (t >= d) ? sc[t - d] : 0;
        __syncthreads();
        sc[t] += add;
        __syncthreads();
    }
    if (t < nbuk) { int o = sc[t] - v; boffs[t] = o; bcur[t] = o; }
}

// ---------- P1: edge-order MFMA MLP + in-place LDS binning, prefetched ----------
// record (32B): h[0..14] = fp16 edge-MLP outputs, h[15] = src_local (raw u16)
__global__ __launch_bounds__(TB1, 8) void k_mlpbin(
    const float* __restrict__ x_t, const float* __restrict__ ea,
    const float* __restrict__ W1, const float* __restrict__ b1,
    const float* __restrict__ W2, const float* __restrict__ b2,
    const int* __restrict__ src, const int* __restrict__ tgt,
    int* __restrict__ bcur, uint* __restrict__ gbin, int E)
{
    __shared__ uint stagw[ABLK * 8];          // 64 KB, swizzled records
    __shared__ int A[MAXBUK];                 // hist -> (gb - st)
    __shared__ int B[MAXBUK];                 // cursor
    __shared__ ushort sbk[ABLK];              // 4 KB
    __shared__ int wsum[16];

    int t = threadIdx.x;
    int lane = t & 63, w = t >> 6;
    int base = blockIdx.x * ABLK;
    int m = min(ABLK, E - base);

    // ---- prefetch: src/tgt for both edges, issued immediately ----
    int i0 = t, i1 = t + TB1;
    bool v0 = (i0 < m), v1 = (i1 < m);
    int e0 = base + (v0 ? i0 : 0);
    int e1 = base + (v1 ? i1 : 0);
    int sv0 = src[e0], tg0 = tgt[e0];
    int sv1 = src[e1], tg1 = tgt[e1];

    // ---- histogram off registers ----
    A[t] = 0;
    __syncthreads();
    if (v0) atomicAdd(&A[sv0 >> BSH], 1);
    if (v1) atomicAdd(&A[sv1 >> BSH], 1);

    // ---- issue feature gathers NOW; latency hides under scan + alloc ----
    float xt0[FXT], xt1[FXT];
    float2 ev0[5], ev1[5];
    {
        const float* xr0 = x_t + (size_t)tg0 * FXT;
        const float* xr1 = x_t + (size_t)tg1 * FXT;
#pragma unroll
        for (int j = 0; j < FXT; j++) { xt0[j] = xr0[j]; xt1[j] = xr1[j]; }
        const float2* er0 = (const float2*)(ea + (size_t)e0 * FE);
        const float2* er1 = (const float2*)(ea + (size_t)e1 * FE);
#pragma unroll
        for (int j = 0; j < 5; j++) { ev0[j] = er0[j]; ev1[j] = er1[j]; }
    }
    __syncthreads();

    // ---- 2-barrier shuffle scan over 1024 bucket counts ----
    int h = A[t];
    int x = h;
#pragma unroll
    for (int d = 1; d < 64; d <<= 1) {
        int y = __shfl_up(x, d, 64);
        if (lane >= d) x += y;
    }
    if (lane == 63) wsum[w] = x;
    __syncthreads();
    if (w == 0) {
        int v = (lane < 16) ? wsum[lane] : 0;
        int xx = v;
#pragma unroll
        for (int d = 1; d < 16; d <<= 1) {
            int y = __shfl_up(xx, d, 64);
            if (lane >= d) xx += y;
        }
        if (lane < 16) wsum[lane] = xx - v;
    }
    __syncthreads();
    int st = wsum[w] + (x - h);
    B[t] = st;
    int gb = h ? atomicAdd(&bcur[t], h) : 0;
    A[t] = gb - st;                           // dst = A[bk] + bin_pos
    __syncthreads();

    // ---- resident weight/bias fragments (layout HW-verified rounds 4-14) ----
    int em = lane & 15;
    int kb = (lane >> 4) << 2;
    int q = kb >> 2;
    half4 a1f, a2f;
    floatx4 c1f, c2f;
#pragma unroll
    for (int i = 0; i < 4; i++) {
        int kk = kb + i;
        bool wv = (kk < H1) && (em < H1);
        a1f[i] = wv ? (_Float16)W1[kk * H1 + em] : (_Float16)0.f;
        a2f[i] = wv ? (_Float16)W2[kk * H1 + em] : (_Float16)0.f;
        c1f[i] = (kk < H1) ? b1[kk] : 0.f;
        c2f[i] = (kk < H1) ? b2[kk] : 0.f;
    }

    // ---- stage from registers (zero global loads here) ----
#define STAGE_EDGE(sv, xt, ev)                                                  \
    {                                                                           \
        int bk = (sv) >> BSH;                                                   \
        int pos = atomicAdd(&B[bk], 1);                                         \
        sbk[pos] = (ushort)bk;                                                  \
        float f[15];                                                            \
        _Pragma("unroll")                                                       \
        for (int j = 0; j < FXT; j++) f[j] = (xt)[j];                           \
        _Pragma("unroll")                                                       \
        for (int j = 0; j < 5; j++) {                                           \
            f[FXT + 2 * j] = (ev)[j].x;                                         \
            f[FXT + 2 * j + 1] = (ev)[j].y;                                     \
        }                                                                       \
        _Pragma("unroll")                                                       \
        for (int c = 0; c < 4; c++) {                                           \
            union { _Float16 hh[4]; ushort us[4]; uint2 u; } pk;                \
            _Pragma("unroll")                                                   \
            for (int j = 0; j < 4; j++) {                                       \
                int fi = c * 4 + j;                                             \
                pk.hh[j] = (fi < 15) ? (_Float16)f[fi] : (_Float16)0.f;         \
            }                                                                   \
            if (c == 3) pk.us[3] = (ushort)((sv) & (NPB - 1));                  \
            *(uint2*)&stagw[sw(pos, c)] = pk.u;                                 \
        }                                                                       \
    }
    if (v0) STAGE_EDGE(sv0, xt0, ev0)
    if (v1) STAGE_EDGE(sv1, xt1, ev1)
#undef STAGE_EDGE
    __syncthreads();

    // ---- MFMA in place: 16 waves x 128 rows ----
#pragma unroll
    for (int g = 0; g < ABLK / (16 * 16); g++) {
        int r = w * 128 + g * 16 + em;
        union { uint2 u; _Float16 hh[4]; } bin_;
        bin_.u = *(uint2*)&stagw[sw(r, q)];
        half4 bf;
#pragma unroll
        for (int j = 0; j < 4; j++) bf[j] = bin_.hh[j];
        floatx4 d1 = __builtin_amdgcn_mfma_f32_16x16x16f16(a1f, bf, c1f, 0, 0, 0);
        half4 hm;
#pragma unroll
        for (int j = 0; j < 4; j++) {
            float xx = d1[j];
            xx = fmaxf(xx, 0.1f * xx);
            hm[j] = (_Float16)xx;
        }
        floatx4 d2 = __builtin_amdgcn_mfma_f32_16x16x16f16(a2f, hm, c2f, 0, 0, 0);
        union { _Float16 hh[4]; ushort us[4]; uint uu[2]; uint2 u; } ov;
#pragma unroll
        for (int j = 0; j < 4; j++) ov.hh[j] = (_Float16)d2[j];
        uint* wp = &stagw[sw(r, q)];
        if (kb < 12) {
            *(uint2*)wp = ov.u;
        } else {
            wp[0] = ov.uu[0];
            ((ushort*)&wp[1])[0] = ov.us[2];        // preserves sid in high half
        }
    }
    __syncthreads();

    // ---- dense write-out: bucket-contiguous global bursts ----
    for (int i = t; i < m; i += TB1) {
        int bk = sbk[i];
        uint2 q0 = *(uint2*)&stagw[sw(i, 0)];
        uint2 q1 = *(uint2*)&stagw[sw(i, 1)];
        uint2 q2 = *(uint2*)&stagw[sw(i, 2)];
        uint2 q3 = *(uint2*)&stagw[sw(i, 3)];
        size_t dst = (size_t)(A[bk] + i) * 8;
        *(uint4*)(gbin + dst)     = make_uint4(q0.x, q0.y, q1.x, q1.y);
        *(uint4*)(gbin + dst + 4) = make_uint4(q2.x, q2.y, q3.x, q3.y);
    }
}

// ---------- P2: fused per-bucket sort-index + moments + node MLP ----------
// One block per 128-node bucket. Sid pass -> LDS histogram/scan -> u16 index
// list in LDS (no record movement). Then 4 lanes per node stream records via
// idx (4x8B = one 32B segment), moments in registers, stats -> feat, block-
// parallel node MLP (epilogue verified R10).
__global__ __launch_bounds__(TBF, 6) void k_fuse(
    const float* __restrict__ x_s, const float* __restrict__ u,
    const float* __restrict__ W3, const float* __restrict__ b3,
    const float* __restrict__ W4, const float* __restrict__ b4,
    const int* __restrict__ batch_s,
    const int* __restrict__ bcnt, const int* __restrict__ boffs,
    const uint* __restrict__ gbin,
    float* __restrict__ out, int NSs)
{
    __shared__ ushort idx[CAPS];               // 10 KB
    __shared__ int fh[NPB], fstart[NPB], fcur[NPB];
    __shared__ float sW3[H2 * FXS], sb3[FXS], sW4[FXS * FXS], sb4[FXS];
    __shared__ float feat[NPB][61];            // [f*4+m] moments->stats; [60]=n
    __shared__ float l1s[NPB][FXS];

    int t = threadIdx.x;
    for (int i = t; i < H2 * FXS; i += TBF) sW3[i] = W3[i];
    for (int i = t; i < FXS * FXS; i += TBF) sW4[i] = W4[i];
    if (t < FXS) { sb3[t] = b3[t]; sb4[t] = b4[t]; }
    if (t < NPB) fh[t] = 0;
    __syncthreads();

    int b = blockIdx.x;
    int base = boffs[b];
    int cnt = min(bcnt[b], CAPS);
    const uint* rb = gbin + (size_t)base * 8;

    // sid histogram
    for (int i = t; i < cnt; i += TBF)
        atomicAdd(&fh[(rb[(size_t)i * 8 + 7] >> 16) & (NPB - 1)], 1);
    __syncthreads();
    if (t < NPB) fstart[t] = fh[t];
    __syncthreads();
    for (int d = 1; d < NPB; d <<= 1) {
        int add = (t < NPB && t >= d) ? fstart[t - d] : 0;
        __syncthreads();
        if (t < NPB) fstart[t] += add;
        __syncthreads();
    }
    if (t < NPB) { int s0 = fstart[t] - fh[t]; fstart[t] = s0; fcur[t] = s0; }
    __syncthreads();
    // index list (node-sorted handles)
    for (int i = t; i < cnt; i += TBF) {
        int sl = (int)(rb[(size_t)i * 8 + 7] >> 16) & (NPB - 1);
        int p = atomicAdd(&fcur[sl], 1);
        idx[p] = (ushort)i;
    }
    __syncthreads();

    // ---- moments: 128 nodes x 4 lanes; lane lq owns features 4lq..4lq+3 ----
    int l = t >> 2, lq = t & 3;
    int s = (b << BSH) + l;
    int n = fh[l], start = fstart[l];

    float s1[4] = {0.f,0.f,0.f,0.f}, s2[4] = {0.f,0.f,0.f,0.f};
    float s3[4] = {0.f,0.f,0.f,0.f}, s4[4] = {0.f,0.f,0.f,0.f};
    if (s < NSs) {
        for (int k = 0; k < n; k++) {
            int ri = idx[start + k];
            uint2 rv = *(const uint2*)(rb + (size_t)ri * 8 + lq * 2);
            union { uint uu[2]; _Float16 h[4]; } up;
            up.uu[0] = rv.x; up.uu[1] = rv.y;
#pragma unroll
            for (int j = 0; j < 4; j++) {
                float x = (float)up.h[j];       // f==15 slot is sid; excluded at write
                float x2 = x * x;
                s1[j] += x;
                s2[j] = fmaf(x, x, s2[j]);
                s3[j] = fmaf(x2, x, s3[j]);
                s4[j] = fmaf(x2, x2, s4[j]);
            }
        }
        float inv = 1.0f / (float)(n > 1 ? n : 1);
#pragma unroll
        for (int j = 0; j < 4; j++) {
            int f = lq * 4 + j;
            if (f < H1) {
                float a = s1[j] * inv, m2 = s2[j] * inv, m3 = s3[j] * inv, m4 = s4[j] * inv;
                float a2 = a * a;
                float var = m2 - a2;
                float bb = sqrtf(1e-6f + fmaxf(var, 0.0f));
                float c3 = m3 - 3.0f * a * m2 + 2.0f * a * a2;
                float c4 = m4 - 4.0f * a * m3 + 6.0f * a2 * m2 - 3.0f * a2 * a2;
                float ib = 1.0f / bb, ib2 = ib * ib;
                feat[l][f * 4 + 0] = a;
                feat[l][f * 4 + 1] = bb;
                feat[l][f * 4 + 2] = c3 * ib * ib2;
                feat[l][f * 4 + 3] = c4 * ib2 * ib2;
            }
        }
        if (lq == 0) feat[l][60] = (float)n;
    }
    __syncthreads();

    // ---- node MLP layer 1 (epilogue pattern verified R10) ----
    for (int id = t; id < NPB * FXS; id += TBF) {
        int g = id / FXS, j = id - g * FXS;
        int ss = (b << BSH) + g;
        if (ss >= NSs) continue;
        const float* ar = feat[g];
        float acc = sb3[j];
        const float* xr = x_s + (size_t)ss * FXS;
#pragma unroll
        for (int i = 0; i < FXS; i++) acc = fmaf(xr[i], sW3[i * FXS + j], acc);
        acc = fmaf(ar[60], sW3[FXS * FXS + j], acc);
#pragma unroll
        for (int f = 0; f < H1; f++) {
            acc = fmaf(ar[f * 4 + 0], sW3[(11 + f) * FXS + j], acc);
            acc = fmaf(ar[f * 4 + 1], sW3[(26 + f) * FXS + j], acc);
            acc = fmaf(ar[f * 4 + 2], sW3[(41 + f) * FXS + j], acc);
            acc = fmaf(ar[f * 4 + 3], sW3[(56 + f) * FXS + j], acc);
        }
        const float* ur = u + (size_t)batch_s[ss] * FU;
#pragma unroll
        for (int i = 0; i < FU; i++) acc = fmaf(ur[i], sW3[(71 + i) * FXS + j], acc);
        l1s[g][j] = fmaxf(acc, 0.1f * acc);
    }
    __syncthreads();

    // ---- node MLP layer 2 + output ----
    for (int id = t; id < NPB * FXS; id += TBF) {
        int g = id / FXS, j = id - g * FXS;
        int ss = (b << BSH) + g;
        if (ss >= NSs) continue;
        float acc = sb4[j];
#pragma unroll
        for (int i = 0; i < FXS; i++) acc = fmaf(l1s[g][i], sW4[i * FXS + j], acc);
        out[(size_t)ss * FXS + j] = acc;
    }
}

extern "C" void kernel_launch(void* const* d_in, const int* in_sizes, int n_in,
                              void* d_out, int out_size, void* d_ws, size_t ws_size,
                              hipStream_t stream) {
    const float* x_s = (const float*)d_in[0];
    const float* x_t = (const float*)d_in[1];
    const float* ea  = (const float*)d_in[2];
    const float* u   = (const float*)d_in[3];
    const float* W1  = (const float*)d_in[4];
    const float* b1  = (const float*)d_in[5];
    const float* W2  = (const float*)d_in[6];
    const float* b2  = (const float*)d_in[7];
    const float* W3  = (const float*)d_in[8];
    const float* b3  = (const float*)d_in[9];
    const float* W4  = (const float*)d_in[10];
    const float* b4  = (const float*)d_in[11];
    const int* src   = (const int*)d_in[12];
    const int* tgt   = (const int*)d_in[13];
    const int* batch_s = (const int*)d_in[14];

    int NSs = in_sizes[0] / FXS;
    int E   = in_sizes[2] / FE;
    int nbuk = (NSs + NPB - 1) >> BSH;

    auto align_up = [](size_t x) { return (x + 255) & ~(size_t)255; };
    char* w = (char*)d_ws;
    int* bcnt   = (int*)w; w += align_up((size_t)MAXBUK * 4);
    int* boffs  = (int*)w; w += align_up((size_t)MAXBUK * 4);
    int* bcur   = (int*)w; w += align_up((size_t)MAXBUK * 4);
    uint* gbin  = (uint*)w;   // E * 32 bytes

    hipMemsetAsync(bcnt, 0, (size_t)MAXBUK * 4, stream);

    k_bhist<<<512, 256, 0, stream>>>(src, bcnt, E, nbuk);
    k_bscan<<<1, 1024, 0, stream>>>(bcnt, boffs, bcur, nbuk);
    k_mlpbin<<<(E + ABLK - 1) / ABLK, TB1, 0, stream>>>(
        x_t, ea, W1, b1, W2, b2, src, tgt, bcur, gbin, E);
    k_fuse<<<nbuk, TBF, 0, stream>>>(
        x_s, u, W3, b3, W4, b4, batch_s, bcnt, boffs, gbin, (float*)d_out, NSs);
}

// Round 16
// 171.882 us; speedup vs baseline: 2.2767x; 1.0943x over previous
//
#include <hip/hip_runtime.h>
#include <hip/hip_fp16.h>

#define H1 15
#define H2 81
#define FXS 10
#define FXT 5
#define FE 10
#define FU 10

#define BSH 8                 // 256 nodes per coarse bucket
#define NPB 256
#define MAXBUK 512            // supports NS up to 131072
#define ABLK 2048             // edges per k_mlpbin block
#define TB1 1024              // producer threads (16 waves)
#define TBF 512               // fused consumer threads
#define CAPS 10240            // records per bucket cap (mean 8184 + ~22 sigma)
#define RPT 20                // CAPS / TBF

typedef _Float16 half4 __attribute__((ext_vector_type(4)));
typedef float floatx4 __attribute__((ext_vector_type(4)));
typedef unsigned int uint;
typedef unsigned short ushort;

// swizzled uint2 slot for record row/quarter (R14-proven)
__device__ __forceinline__ int sw(int row, int q) {
    return row * 8 + 2 * (q ^ ((row >> 2) & 3));
}

// ---------- bucket histogram ----------
__global__ __launch_bounds__(256) void k_bhist(const int* __restrict__ src,
                                               int* __restrict__ bcnt, int E, int nbuk) {
    __shared__ int h[MAXBUK];
    for (int i = threadIdx.x; i < MAXBUK; i += 256) h[i] = 0;
    __syncthreads();
    for (int i = blockIdx.x * blockDim.x + threadIdx.x; i < E; i += gridDim.x * blockDim.x)
        atomicAdd(&h[src[i] >> BSH], 1);
    __syncthreads();
    for (int i = threadIdx.x; i < nbuk; i += 256)
        if (h[i]) atomicAdd(&bcnt[i], h[i]);
}

// ---------- bucket exclusive scan ----------
__global__ __launch_bounds__(MAXBUK) void k_bscan(const int* __restrict__ bcnt,
                                                  int* __restrict__ boffs,
                                                  int* __restrict__ bcur, int nbuk) {
    __shared__ int sc[MAXBUK];
    int t = threadIdx.x;
    int v = (t < nbuk) ? bcnt[t] : 0;
    sc[t] = v;
    __syncthreads();
    for (int d = 1; d < MAXBUK; d <<= 1) {
        int add = (t >= d) ? sc[t - d] : 0;
        __syncthreads();
        sc[t] += add;
        __syncthreads();
    }
    if (t < nbuk) { int o = sc[t] - v; boffs[t] = o; bcur[t] = o; }
}

// ---------- P1: edge-order MFMA MLP + in-place LDS binning, prefetched ----------
// record (32B): h[0..14] = fp16 edge-MLP outputs, h[15] = src_local (raw u16)
__global__ __launch_bounds__(TB1, 8) void k_mlpbin(
    const float* __restrict__ x_t, const float* __restrict__ ea,
    const float* __restrict__ W1, const float* __restrict__ b1,
    const float* __restrict__ W2, const float* __restrict__ b2,
    const int* __restrict__ src, const int* __restrict__ tgt,
    int* __restrict__ bcur, uint* __restrict__ gbin, int E)
{
    __shared__ uint stagw[ABLK * 8];          // 64 KB, swizzled records
    __shared__ int A[MAXBUK];                 // hist -> (gb - st)
    __shared__ int B[MAXBUK];                 // cursor
    __shared__ ushort sbk[ABLK];              // 4 KB
    __shared__ int wsum[8];

    int t = threadIdx.x;
    int lane = t & 63, w = t >> 6;
    int base = blockIdx.x * ABLK;
    int m = min(ABLK, E - base);

    // ---- prefetch: src/tgt for both edges, issued immediately ----
    int i0 = t, i1 = t + TB1;
    bool v0 = (i0 < m), v1 = (i1 < m);
    int e0 = base + (v0 ? i0 : 0);
    int e1 = base + (v1 ? i1 : 0);
    int sv0 = src[e0], tg0 = tgt[e0];
    int sv1 = src[e1], tg1 = tgt[e1];

    // ---- histogram off registers ----
    if (t < MAXBUK) A[t] = 0;
    __syncthreads();
    if (v0) atomicAdd(&A[sv0 >> BSH], 1);
    if (v1) atomicAdd(&A[sv1 >> BSH], 1);

    // ---- issue feature gathers NOW; latency hides under scan + alloc ----
    float xt0[FXT], xt1[FXT];
    float2 ev0[5], ev1[5];
    {
        const float* xr0 = x_t + (size_t)tg0 * FXT;
        const float* xr1 = x_t + (size_t)tg1 * FXT;
#pragma unroll
        for (int j = 0; j < FXT; j++) { xt0[j] = xr0[j]; xt1[j] = xr1[j]; }
        const float2* er0 = (const float2*)(ea + (size_t)e0 * FE);
        const float2* er1 = (const float2*)(ea + (size_t)e1 * FE);
#pragma unroll
        for (int j = 0; j < 5; j++) { ev0[j] = er0[j]; ev1[j] = er1[j]; }
    }
    __syncthreads();

    // ---- 2-barrier shuffle scan over 512 bucket counts (8 waves active) ----
    int h = 0, x = 0;
    if (t < MAXBUK) { h = A[t]; x = h; }
#pragma unroll
    for (int d = 1; d < 64; d <<= 1) {
        int y = __shfl_up(x, d, 64);
        if (lane >= d) x += y;
    }
    if (t < MAXBUK && lane == 63) wsum[w] = x;
    __syncthreads();
    if (w == 0) {
        int v = (lane < 8) ? wsum[lane] : 0;
        int xx = v;
#pragma unroll
        for (int d = 1; d < 8; d <<= 1) {
            int y = __shfl_up(xx, d, 64);
            if (lane >= d) xx += y;
        }
        if (lane < 8) wsum[lane] = xx - v;
    }
    __syncthreads();
    if (t < MAXBUK) {
        int st = wsum[w] + (x - h);
        B[t] = st;
        int gb = h ? atomicAdd(&bcur[t], h) : 0;
        A[t] = gb - st;                       // dst = A[bk] + bin_pos
    }
    __syncthreads();

    // ---- resident weight/bias fragments (layout HW-verified rounds 4-15) ----
    int em = lane & 15;
    int kb = (lane >> 4) << 2;
    int q = kb >> 2;
    half4 a1f, a2f;
    floatx4 c1f, c2f;
#pragma unroll
    for (int i = 0; i < 4; i++) {
        int kk = kb + i;
        bool wv = (kk < H1) && (em < H1);
        a1f[i] = wv ? (_Float16)W1[kk * H1 + em] : (_Float16)0.f;
        a2f[i] = wv ? (_Float16)W2[kk * H1 + em] : (_Float16)0.f;
        c1f[i] = (kk < H1) ? b1[kk] : 0.f;
        c2f[i] = (kk < H1) ? b2[kk] : 0.f;
    }

    // ---- stage from registers (zero global loads here) ----
#define STAGE_EDGE(sv, xt, ev)                                                  \
    {                                                                           \
        int bk = (sv) >> BSH;                                                   \
        int pos = atomicAdd(&B[bk], 1);                                         \
        sbk[pos] = (ushort)bk;                                                  \
        float f[15];                                                            \
        _Pragma("unroll")                                                       \
        for (int j = 0; j < FXT; j++) f[j] = (xt)[j];                           \
        _Pragma("unroll")                                                       \
        for (int j = 0; j < 5; j++) {                                           \
            f[FXT + 2 * j] = (ev)[j].x;                                         \
            f[FXT + 2 * j + 1] = (ev)[j].y;                                     \
        }                                                                       \
        _Pragma("unroll")                                                       \
        for (int c = 0; c < 4; c++) {                                           \
            union { _Float16 hh[4]; ushort us[4]; uint2 u; } pk;                \
            _Pragma("unroll")                                                   \
            for (int j = 0; j < 4; j++) {                                       \
                int fi = c * 4 + j;                                             \
                pk.hh[j] = (fi < 15) ? (_Float16)f[fi] : (_Float16)0.f;         \
            }                                                                   \
            if (c == 3) pk.us[3] = (ushort)((sv) & (NPB - 1));                  \
            *(uint2*)&stagw[sw(pos, c)] = pk.u;                                 \
        }                                                                       \
    }
    if (v0) STAGE_EDGE(sv0, xt0, ev0)
    if (v1) STAGE_EDGE(sv1, xt1, ev1)
#undef STAGE_EDGE
    __syncthreads();

    // ---- MFMA in place: 16 waves x 128 rows ----
#pragma unroll
    for (int g = 0; g < ABLK / (16 * 16); g++) {
        int r = w * 128 + g * 16 + em;
        union { uint2 u; _Float16 hh[4]; } bin_;
        bin_.u = *(uint2*)&stagw[sw(r, q)];
        half4 bf;
#pragma unroll
        for (int j = 0; j < 4; j++) bf[j] = bin_.hh[j];
        floatx4 d1 = __builtin_amdgcn_mfma_f32_16x16x16f16(a1f, bf, c1f, 0, 0, 0);
        half4 hm;
#pragma unroll
        for (int j = 0; j < 4; j++) {
            float xx = d1[j];
            xx = fmaxf(xx, 0.1f * xx);
            hm[j] = (_Float16)xx;
        }
        floatx4 d2 = __builtin_amdgcn_mfma_f32_16x16x16f16(a2f, hm, c2f, 0, 0, 0);
        union { _Float16 hh[4]; ushort us[4]; uint uu[2]; uint2 u; } ov;
#pragma unroll
        for (int j = 0; j < 4; j++) ov.hh[j] = (_Float16)d2[j];
        uint* wp = &stagw[sw(r, q)];
        if (kb < 12) {
            *(uint2*)wp = ov.u;
        } else {
            wp[0] = ov.uu[0];
            ((ushort*)&wp[1])[0] = ov.us[2];        // preserves sid in high half
        }
    }
    __syncthreads();

    // ---- dense write-out: bucket-contiguous global bursts (~168B now) ----
    for (int i = t; i < m; i += TB1) {
        int bk = sbk[i];
        uint2 q0 = *(uint2*)&stagw[sw(i, 0)];
        uint2 q1 = *(uint2*)&stagw[sw(i, 1)];
        uint2 q2 = *(uint2*)&stagw[sw(i, 2)];
        uint2 q3 = *(uint2*)&stagw[sw(i, 3)];
        size_t dst = (size_t)(A[bk] + i) * 8;
        *(uint4*)(gbin + dst)     = make_uint4(q0.x, q0.y, q1.x, q1.y);
        *(uint4*)(gbin + dst + 4) = make_uint4(q2.x, q2.y, q3.x, q3.y);
    }
}

// ---------- P2: fused per-bucket (256 nodes) sort-index + moments + node MLP ----------
// Sid pass register-staged (one strided read serves hist AND placement).
// Moments+MLP in two 128-node passes sharing the idx list.
__global__ __launch_bounds__(TBF, 4) void k_fuse(
    const float* __restrict__ x_s, const float* __restrict__ u,
    const float* __restrict__ W3, const float* __restrict__ b3,
    const float* __restrict__ W4, const float* __restrict__ b4,
    const int* __restrict__ batch_s,
    const int* __restrict__ bcnt, const int* __restrict__ boffs,
    const uint* __restrict__ gbin,
    float* __restrict__ out, int NSs)
{
    __shared__ ushort idx[CAPS];               // 20 KB
    __shared__ int fh[NPB], fstart[NPB], fcur[NPB];   // 3 KB
    __shared__ float sW3[H2 * FXS], sb3[FXS], sW4[FXS * FXS], sb4[FXS];
    __shared__ float feat[128][61];            // 31.2 KB (per 128-node pass)
    __shared__ float l1s[128][FXS];            // 5 KB

    int t = threadIdx.x;
    for (int i = t; i < H2 * FXS; i += TBF) sW3[i] = W3[i];
    for (int i = t; i < FXS * FXS; i += TBF) sW4[i] = W4[i];
    if (t < FXS) { sb3[t] = b3[t]; sb4[t] = b4[t]; }
    if (t < NPB) fh[t] = 0;
    __syncthreads();

    int b = blockIdx.x;
    int base = boffs[b];
    int cnt = min(bcnt[b], CAPS);
    const uint* rb = gbin + (size_t)base * 8;

    // register-staged sid pass: hist
    int sid[RPT];
#pragma unroll
    for (int c = 0; c < RPT; c++) {
        int i = t + c * TBF;
        sid[c] = -1;
        if (i < cnt) {
            sid[c] = (int)(rb[(size_t)i * 8 + 7] >> 16) & (NPB - 1);
            atomicAdd(&fh[sid[c]], 1);
        }
    }
    __syncthreads();
    if (t < NPB) fstart[t] = fh[t];
    __syncthreads();
    for (int d = 1; d < NPB; d <<= 1) {
        int add = (t < NPB && t >= d) ? fstart[t - d] : 0;
        __syncthreads();
        if (t < NPB) fstart[t] += add;
        __syncthreads();
    }
    if (t < NPB) { int s0 = fstart[t] - fh[t]; fstart[t] = s0; fcur[t] = s0; }
    __syncthreads();
    // placement from registers
#pragma unroll
    for (int c = 0; c < RPT; c++) {
        if (sid[c] >= 0) {
            int p = atomicAdd(&fcur[sid[c]], 1);
            idx[p] = (ushort)(t + c * TBF);
        }
    }
    __syncthreads();

    // ---- two 128-node passes: moments + stats + node MLP ----
    for (int pass = 0; pass < 2; pass++) {
        int l = t >> 2, lq = t & 3;            // 128 nodes x 4 lanes
        int ln = pass * 128 + l;               // local node in bucket
        int s = (b << BSH) + ln;
        int n = fh[ln], start = fstart[ln];

        float s1[4] = {0.f,0.f,0.f,0.f}, s2[4] = {0.f,0.f,0.f,0.f};
        float s3[4] = {0.f,0.f,0.f,0.f}, s4[4] = {0.f,0.f,0.f,0.f};
        if (s < NSs) {
            for (int k = 0; k < n; k++) {
                int ri = idx[start + k];
                uint2 rv = *(const uint2*)(rb + (size_t)ri * 8 + lq * 2);
                union { uint uu[2]; _Float16 h[4]; } up;
                up.uu[0] = rv.x; up.uu[1] = rv.y;
#pragma unroll
                for (int j = 0; j < 4; j++) {
                    float x = (float)up.h[j];   // f==15 slot is sid; excluded at write
                    float x2 = x * x;
                    s1[j] += x;
                    s2[j] = fmaf(x, x, s2[j]);
                    s3[j] = fmaf(x2, x, s3[j]);
                    s4[j] = fmaf(x2, x2, s4[j]);
                }
            }
            float inv = 1.0f / (float)(n > 1 ? n : 1);
#pragma unroll
            for (int j = 0; j < 4; j++) {
                int f = lq * 4 + j;
                if (f < H1) {
                    float a = s1[j] * inv, m2 = s2[j] * inv, m3 = s3[j] * inv, m4 = s4[j] * inv;
                    float a2 = a * a;
                    float var = m2 - a2;
                    float bb = sqrtf(1e-6f + fmaxf(var, 0.0f));
                    float c3 = m3 - 3.0f * a * m2 + 2.0f * a * a2;
                    float c4 = m4 - 4.0f * a * m3 + 6.0f * a2 * m2 - 3.0f * a2 * a2;
                    float ib = 1.0f / bb, ib2 = ib * ib;
                    feat[l][f * 4 + 0] = a;
                    feat[l][f * 4 + 1] = bb;
                    feat[l][f * 4 + 2] = c3 * ib * ib2;
                    feat[l][f * 4 + 3] = c4 * ib2 * ib2;
                }
            }
            if (lq == 0) feat[l][60] = (float)n;
        }
        __syncthreads();

        // node MLP layer 1 (epilogue pattern verified R10)
        for (int id = t; id < 128 * FXS; id += TBF) {
            int g = id / FXS, j = id - g * FXS;
            int ss = (b << BSH) + pass * 128 + g;
            if (ss >= NSs) continue;
            const float* ar = feat[g];
            float acc = sb3[j];
            const float* xr = x_s + (size_t)ss * FXS;
#pragma unroll
            for (int i = 0; i < FXS; i++) acc = fmaf(xr[i], sW3[i * FXS + j], acc);
            acc = fmaf(ar[60], sW3[FXS * FXS + j], acc);
#pragma unroll
            for (int f = 0; f < H1; f++) {
                acc = fmaf(ar[f * 4 + 0], sW3[(11 + f) * FXS + j], acc);
                acc = fmaf(ar[f * 4 + 1], sW3[(26 + f) * FXS + j], acc);
                acc = fmaf(ar[f * 4 + 2], sW3[(41 + f) * FXS + j], acc);
                acc = fmaf(ar[f * 4 + 3], sW3[(56 + f) * FXS + j], acc);
            }
            const float* ur = u + (size_t)batch_s[ss] * FU;
#pragma unroll
            for (int i = 0; i < FU; i++) acc = fmaf(ur[i], sW3[(71 + i) * FXS + j], acc);
            l1s[g][j] = fmaxf(acc, 0.1f * acc);
        }
        __syncthreads();

        // node MLP layer 2 + output
        for (int id = t; id < 128 * FXS; id += TBF) {
            int g = id / FXS, j = id - g * FXS;
            int ss = (b << BSH) + pass * 128 + g;
            if (ss >= NSs) continue;
            float acc = sb4[j];
#pragma unroll
            for (int i = 0; i < FXS; i++) acc = fmaf(l1s[g][i], sW4[i * FXS + j], acc);
            out[(size_t)ss * FXS + j] = acc;
        }
        __syncthreads();   // feat/l1s reused next pass
    }
}

extern "C" void kernel_launch(void* const* d_in, const int* in_sizes, int n_in,
                              void* d_out, int out_size, void* d_ws, size_t ws_size,
                              hipStream_t stream) {
    const float* x_s = (const float*)d_in[0];
    const float* x_t = (const float*)d_in[1];
    const float* ea  = (const float*)d_in[2];
    const float* u   = (const float*)d_in[3];
    const float* W1  = (const float*)d_in[4];
    const float* b1  = (const float*)d_in[5];
    const float* W2  = (const float*)d_in[6];
    const float* b2  = (const float*)d_in[7];
    const float* W3  = (const float*)d_in[8];
    const float* b3  = (const float*)d_in[9];
    const float* W4  = (const float*)d_in[10];
    const float* b4  = (const float*)d_in[11];
    const int* src   = (const int*)d_in[12];
    const int* tgt   = (const int*)d_in[13];
    const int* batch_s = (const int*)d_in[14];

    int NSs = in_sizes[0] / FXS;
    int E   = in_sizes[2] / FE;
    int nbuk = (NSs + NPB - 1) >> BSH;

    auto align_up = [](size_t x) { return (x + 255) & ~(size_t)255; };
    char* w = (char*)d_ws;
    int* bcnt   = (int*)w; w += align_up((size_t)MAXBUK * 4);
    int* boffs  = (int*)w; w += align_up((size_t)MAXBUK * 4);
    int* bcur   = (int*)w; w += align_up((size_t)MAXBUK * 4);
    uint* gbin  = (uint*)w;   // E * 32 bytes

    hipMemsetAsync(bcnt, 0, (size_t)MAXBUK * 4, stream);

    k_bhist<<<512, 256, 0, stream>>>(src, bcnt, E, nbuk);
    k_bscan<<<1, MAXBUK, 0, stream>>>(bcnt, boffs, bcur, nbuk);
    k_mlpbin<<<(E + ABLK - 1) / ABLK, TB1, 0, stream>>>(
        x_t, ea, W1, b1, W2, b2, src, tgt, bcur, gbin, E);
    k_fuse<<<nbuk, TBF, 0, stream>>>(
        x_s, u, W3, b3, W4, b4, batch_s, bcnt, boffs, gbin, (float*)d_out, NSs);
}